// Round 10
// baseline (162.352 us; speedup 1.0000x reference)
//
#include <hip/hip_runtime.h>
#include <hip/hip_cooperative_groups.h>
#include <math.h>

#define N_POINTS   262144
#define NUM_FREQS  10
#define NUM_VOXELS 512

// W is (1536,63) row-major fp32; voxel v uses rows 3v..3v+2 (189 floats).
// Packed in ws as fp16: Wp[v] = 3 rows x 64 halfs (col63 zero) = 384 B,
// 64B-aligned -> per-point gather = 24 uint4 loads over exactly 6 lines.
//
// R10 = R9 skeleton (block-local counting sort -> shared gather lines;
// LDS unpermute -> coalesced out-writes; fp16 + v_dot2_f32_f16) fused into
// ONE cooperative kernel: each block packs 1/256th of Wp, does its sort
// (Wp-independent), grid.sync(), then gathers. Kills the pack_w dispatch
// gap and hides packing behind the sort phase.

typedef _Float16 half2v __attribute__((ext_vector_type(2)));

__device__ __forceinline__ half2v u2h(unsigned int u) {
    union { unsigned int u; half2v h; } c; c.u = u; return c.h;
}

__device__ __forceinline__ float dot2acc(half2v a, half2v b, float acc) {
#if __has_builtin(__builtin_amdgcn_fdot2)
    return __builtin_amdgcn_fdot2(a, b, acc, false);
#else
    return acc + (float)a[0] * (float)b[0] + (float)a[1] * (float)b[1];
#endif
}

// posenc (double-angle recurrence; 2^f*x exact in fp32, recurrence err ~1e-4)
// packed to half2, + dot against 3 fp16 rows of voxel v (24 uint4, 6 lines).
__device__ __forceinline__ void posenc_pack_dot(
    float x0, float x1, float x2, const _Float16* __restrict__ Wp, int v,
    float& a0, float& a1, float& a2)
{
    half2v eh[32];                       // 64 halfs = 16 VGPRs
#define SETE(p, val) eh[(p) >> 1][(p) & 1] = (_Float16)(val)
    SETE(0, x0); SETE(1, x1); SETE(2, x2);
    SETE(63, 0.0f);                      // pairs with zero pad col

    float s0, c0, s1, c1, s2, c2;
    __sincosf(x0, &s0, &c0);
    __sincosf(x1, &s1, &c1);
    __sincosf(x2, &s2, &c2);
    #pragma unroll
    for (int f = 0; f < NUM_FREQS; ++f) {
        const int b = 3 + 6*f;           // [s0 s1 s2 c0 c1 c2]
        SETE(b+0, s0); SETE(b+1, s1); SETE(b+2, s2);
        SETE(b+3, c0); SETE(b+4, c1); SETE(b+5, c2);
        if (f < NUM_FREQS - 1) {
            const float ns0 = 2.0f*s0*c0, nc0 = c0*c0 - s0*s0;
            const float ns1 = 2.0f*s1*c1, nc1 = c1*c1 - s1*s1;
            const float ns2 = 2.0f*s2*c2, nc2 = c2*c2 - s2*s2;
            s0 = ns0; c0 = nc0; s1 = ns1; c1 = nc1; s2 = ns2; c2 = nc2;
        }
    }
#undef SETE

    const uint4* __restrict__ wb = (const uint4*)(Wp + (size_t)v * 192);
    float acc[3];
    #pragma unroll
    for (int r = 0; r < 3; ++r) {
        float a = 0.0f;
        #pragma unroll
        for (int k = 0; k < 8; ++k) {
            const uint4 q = wb[r * 8 + k];
            a = dot2acc(u2h(q.x), eh[4*k + 0], a);
            a = dot2acc(u2h(q.y), eh[4*k + 1], a);
            a = dot2acc(u2h(q.z), eh[4*k + 2], a);
            a = dot2acc(u2h(q.w), eh[4*k + 3], a);
        }
        acc[r] = a;
    }
    a0 = acc[0]; a1 = acc[1]; a2 = acc[2];
}

// ---------------------------------------------------------------------------
// Main kernel. COOP=true: packs Wp in-kernel + grid sync (cooperative
// launch, 256 blocks = 1/CU, co-residency guaranteed). COOP=false: Wp
// pre-packed by pack_w (two-launch fallback).
// ---------------------------------------------------------------------------
template <bool COOP>
__global__ __launch_bounds__(1024) void voxlin_k(
    const float* __restrict__ X,
    _Float16* __restrict__ Wp,
    const int* __restrict__ row_ids,
    const int* __restrict__ voxel_ids,
    float* __restrict__ out,
    const float* __restrict__ W)
{
    __shared__ float4 pts[1024];         // 16 KB: (x,y,z,v) then (a0,a1,a2,-)
    __shared__ int    hist[NUM_VOXELS];
    __shared__ int    cur[NUM_VOXELS];
    __shared__ int    wsum[8];

    const int t    = threadIdx.x;
    const int lane = t & 63;
    const int wid  = t >> 6;
    const int i    = blockIdx.x * 1024 + t;

    // phase 0 (COOP): pack this block's 384-element slice of Wp (overlaps
    // with the Wp-independent sort below; visible to all after grid sync)
    if (COOP) {
        if (t < 384) {
            const int gid = blockIdx.x * 384 + t;    // 256*384 = 98304 = 512*192
            const int v = gid / 192, e = gid % 192;
            const int row = e >> 6, col = e & 63;
            Wp[v * 192 + e] = (col < 63) ? (_Float16)W[v * 189 + row * 63 + col]
                                         : (_Float16)0.0f;
        }
    }

    const int   v  = voxel_ids[i];
    const float x0 = X[3*i + 0];
    const float x1 = X[3*i + 1];
    const float x2 = X[3*i + 2];
    const int   r  = row_ids[i];         // stays in this thread's registers

    if (t < NUM_VOXELS) hist[t] = 0;
    __syncthreads();                                         // B1
    atomicAdd(&hist[v], 1);
    __syncthreads();                                         // B2

    // two-level exclusive scan over 512 bins (waves 0..7 active for level 1)
    int c = 0, incl = 0;
    if (t < NUM_VOXELS) {
        c = hist[t];
        incl = c;
        #pragma unroll
        for (int d = 1; d < 64; d <<= 1) {
            int n = __shfl_up(incl, d);
            if (lane >= d) incl += n;
        }
        if (lane == 63) wsum[wid] = incl;                    // wave totals
    }
    __syncthreads();                                         // B3
    if (t < 64) {                                            // wave 0
        int s = (lane < 8) ? wsum[lane] : 0;
        #pragma unroll
        for (int d = 1; d < 8; d <<= 1) {
            int n = __shfl_up(s, d);
            if (lane >= d) s += n;
        }
        int excl = __shfl_up(s, 1);
        if (lane == 0) excl = 0;
        if (lane < 8) wsum[lane] = excl;                     // chunk offsets
    }
    __syncthreads();                                         // B4
    if (t < NUM_VOXELS) cur[t] = wsum[wid] + incl - c;       // exclusive prefix
    __syncthreads();                                         // B5

    const int mypos = atomicAdd(&cur[v], 1);     // own point's sorted slot
    pts[mypos] = make_float4(x0, x1, x2, __int_as_float(v));
    __syncthreads();                                         // B6

    if (COOP) {
        __threadfence();                          // publish Wp slice
        cooperative_groups::this_grid().sync();   // all packs complete
    }

    // compute for the point sitting at slot t
    const float4 q  = pts[t];
    const int    sv = __float_as_int(q.w);
    float a0, a1, a2;
    posenc_pack_dot(q.x, q.y, q.z, Wp, sv, a0, a1, a2);

    pts[t] = make_float4(a0, a1, a2, 0.0f);      // same slot we read: no race
    __syncthreads();                                         // B7

    // unpermute: fetch own point's result, write in original (coalesced) order
    const float4 res = pts[mypos];
    out[3*r + 0] = res.x;
    out[3*r + 1] = res.y;
    out[3*r + 2] = res.z;
}

// ---------------------------------------------------------------------------
// pack_w for the non-cooperative fallback path.
// ---------------------------------------------------------------------------
__global__ __launch_bounds__(1024) void pack_w(
    const float* __restrict__ W, _Float16* __restrict__ Wp)
{
    const int gid = blockIdx.x * 1024 + threadIdx.x;   // [0, 98304)
    const int v = gid / 192, e = gid % 192;
    const int row = e >> 6, col = e & 63;
    Wp[v * 192 + e] = (col < 63) ? (_Float16)W[v * 189 + row * 63 + col]
                                 : (_Float16)0.0f;
}

// ---------------------------------------------------------------------------
// R1-style fallback if ws too small for the 192 KB packed table.
// ---------------------------------------------------------------------------
__global__ __launch_bounds__(256) void voxlin_fallback(
    const float* __restrict__ X, const float* __restrict__ W,
    const int* __restrict__ row_ids, const int* __restrict__ voxel_ids,
    float* __restrict__ out)
{
    const int i = blockIdx.x * 256 + threadIdx.x;
    if (i >= N_POINTS) return;
    const float x0 = X[3*i], x1 = X[3*i+1], x2 = X[3*i+2];
    const int v = voxel_ids[i];
    const float* __restrict__ w0 = W + v * 189;
    const float* __restrict__ w1 = w0 + 63;
    const float* __restrict__ w2 = w0 + 126;
    float a0 = x0*w0[0] + x1*w0[1] + x2*w0[2];
    float a1 = x0*w1[0] + x1*w1[1] + x2*w1[2];
    float a2 = x0*w2[0] + x1*w2[1] + x2*w2[2];
    float s0, c0, s1, c1, s2, c2;
    __sincosf(x0, &s0, &c0); __sincosf(x1, &s1, &c1); __sincosf(x2, &s2, &c2);
    #pragma unroll
    for (int f = 0; f < NUM_FREQS; ++f) {
        const int b = 3 + 6*f;
        a0 += s0*w0[b] + s1*w0[b+1] + s2*w0[b+2] + c0*w0[b+3] + c1*w0[b+4] + c2*w0[b+5];
        a1 += s0*w1[b] + s1*w1[b+1] + s2*w1[b+2] + c0*w1[b+3] + c1*w1[b+4] + c2*w1[b+5];
        a2 += s0*w2[b] + s1*w2[b+1] + s2*w2[b+2] + c0*w2[b+3] + c1*w2[b+4] + c2*w2[b+5];
        if (f < NUM_FREQS - 1) {
            const float ns0 = 2.0f*s0*c0, nc0 = c0*c0 - s0*s0;
            const float ns1 = 2.0f*s1*c1, nc1 = c1*c1 - s1*s1;
            const float ns2 = 2.0f*s2*c2, nc2 = c2*c2 - s2*s2;
            s0 = ns0; c0 = nc0; s1 = ns1; c1 = nc1; s2 = ns2; c2 = nc2;
        }
    }
    const int rr = row_ids[i];
    out[3*rr] = a0; out[3*rr+1] = a1; out[3*rr+2] = a2;
}

// ---------------------------------------------------------------------------
extern "C" void kernel_launch(void* const* d_in, const int* in_sizes, int n_in,
                              void* d_out, int out_size, void* d_ws, size_t ws_size,
                              hipStream_t stream) {
    const float* X         = (const float*)d_in[0];
    const float* W         = (const float*)d_in[1];
    const int*   row_ids   = (const int*)d_in[2];
    const int*   voxel_ids = (const int*)d_in[3];
    float*       out       = (float*)d_out;

    const size_t need = (size_t)NUM_VOXELS * 192 * sizeof(_Float16); // 192 KB

    if (ws_size >= need) {
        _Float16* Wp = (_Float16*)d_ws;
        void* args[] = { (void*)&X, (void*)&Wp, (void*)&row_ids,
                         (void*)&voxel_ids, (void*)&out, (void*)&W };
        hipError_t err = hipLaunchCooperativeKernel(
            (void*)voxlin_k<true>, dim3(N_POINTS / 1024), dim3(1024),
            args, 0, stream);
        if (err != hipSuccess) {
            // two-launch fallback (R9 path)
            pack_w<<<96, 1024, 0, stream>>>(W, Wp);
            voxlin_k<false><<<N_POINTS / 1024, 1024, 0, stream>>>(
                X, Wp, row_ids, voxel_ids, out, W);
        }
    } else {
        voxlin_fallback<<<(N_POINTS + 255) / 256, 256, 0, stream>>>(X, W, row_ids, voxel_ids, out);
    }
}

// Round 11
// 74.949 us; speedup vs baseline: 2.1662x; 2.1662x over previous
//
#include <hip/hip_runtime.h>
#include <math.h>

#define N_POINTS   262144
#define NUM_FREQS  10
#define NUM_VOXELS 512
#define BLK        512            // threads per block = sort window
#define NBLK       (N_POINTS / BLK)   // 512 blocks -> 2 blocks/CU

// W is (1536,63) row-major fp32; voxel v uses rows 3v..3v+2 (189 floats).
// Packed in ws as fp16: Wp[v] = 3 rows x 64 halfs (col63 zero) = 384 B,
// 64B-aligned -> per-point gather = 24 uint4 loads over exactly 6 lines.
//
// R11 = R9 skeleton (block-local counting sort -> shared gather lines;
// LDS unpermute -> coalesced out-writes; fp16 + v_dot2_f32_f16) with
// 512-thread blocks: grid 512 on 256 CUs = 2 independent blocks/CU, so one
// block's barrier stalls overlap the other block's compute (R9's single
// 16-wave block idled the whole CU at each barrier). Trade-off: window 512
// halves sort density (~+30% gather line-txns) -- prediction is the
// decoupling wins. R10's cooperative grid-sync (80us!) is abandoned.

typedef _Float16 half2v __attribute__((ext_vector_type(2)));

__device__ __forceinline__ half2v u2h(unsigned int u) {
    union { unsigned int u; half2v h; } c; c.u = u; return c.h;
}

__device__ __forceinline__ float dot2acc(half2v a, half2v b, float acc) {
#if __has_builtin(__builtin_amdgcn_fdot2)
    return __builtin_amdgcn_fdot2(a, b, acc, false);
#else
    return acc + (float)a[0] * (float)b[0] + (float)a[1] * (float)b[1];
#endif
}

// posenc (double-angle recurrence; 2^f*x exact in fp32, recurrence err ~1e-4)
// packed to half2, + dot against 3 fp16 rows of voxel v (24 uint4, 6 lines).
__device__ __forceinline__ void posenc_pack_dot(
    float x0, float x1, float x2, const _Float16* __restrict__ Wp, int v,
    float& a0, float& a1, float& a2)
{
    half2v eh[32];                       // 64 halfs = 16 VGPRs
#define SETE(p, val) eh[(p) >> 1][(p) & 1] = (_Float16)(val)
    SETE(0, x0); SETE(1, x1); SETE(2, x2);
    SETE(63, 0.0f);                      // pairs with zero pad col

    float s0, c0, s1, c1, s2, c2;
    __sincosf(x0, &s0, &c0);
    __sincosf(x1, &s1, &c1);
    __sincosf(x2, &s2, &c2);
    #pragma unroll
    for (int f = 0; f < NUM_FREQS; ++f) {
        const int b = 3 + 6*f;           // [s0 s1 s2 c0 c1 c2]
        SETE(b+0, s0); SETE(b+1, s1); SETE(b+2, s2);
        SETE(b+3, c0); SETE(b+4, c1); SETE(b+5, c2);
        if (f < NUM_FREQS - 1) {
            const float ns0 = 2.0f*s0*c0, nc0 = c0*c0 - s0*s0;
            const float ns1 = 2.0f*s1*c1, nc1 = c1*c1 - s1*s1;
            const float ns2 = 2.0f*s2*c2, nc2 = c2*c2 - s2*s2;
            s0 = ns0; c0 = nc0; s1 = ns1; c1 = nc1; s2 = ns2; c2 = nc2;
        }
    }
#undef SETE

    const uint4* __restrict__ wb = (const uint4*)(Wp + (size_t)v * 192);
    float acc[3];
    #pragma unroll
    for (int r = 0; r < 3; ++r) {
        float a = 0.0f;
        #pragma unroll
        for (int k = 0; k < 8; ++k) {
            const uint4 q = wb[r * 8 + k];
            a = dot2acc(u2h(q.x), eh[4*k + 0], a);
            a = dot2acc(u2h(q.y), eh[4*k + 1], a);
            a = dot2acc(u2h(q.z), eh[4*k + 2], a);
            a = dot2acc(u2h(q.w), eh[4*k + 3], a);
        }
        acc[r] = a;
    }
    a0 = acc[0]; a1 = acc[1]; a2 = acc[2];
}

// ---------------------------------------------------------------------------
// Pass 1: pack W (fp32 1536x63) -> Wp (fp16 512 x 3 x 64). Runs every call
// (ws is re-poisoned before every timed launch).
// ---------------------------------------------------------------------------
__global__ __launch_bounds__(1024) void pack_w(
    const float* __restrict__ W, _Float16* __restrict__ Wp)
{
    const int gid = blockIdx.x * 1024 + threadIdx.x;   // [0, 98304) = 512*192
    const int v = gid / 192, e = gid % 192;
    const int row = e >> 6, col = e & 63;
    Wp[v * 192 + e] = (col < 63) ? (_Float16)W[v * 189 + row * 63 + col]
                                 : (_Float16)0.0f;
}

// ---------------------------------------------------------------------------
// Pass 2: fused sort + compute + unpermute. Grid = 512 x 512 = N.
// 2 blocks/CU (VGPR ~36 << 64, launch_bounds(512,8) guarantees 8 waves/EU
// capacity) -> independent barrier domains overlap.
// ---------------------------------------------------------------------------
__global__ __launch_bounds__(BLK, 8) void voxlin_fused(
    const float* __restrict__ X,
    const _Float16* __restrict__ Wp,
    const int* __restrict__ row_ids,
    const int* __restrict__ voxel_ids,
    float* __restrict__ out)
{
    __shared__ float4 pts[BLK];          // 8 KB: (x,y,z,v) then (a0,a1,a2,-)
    __shared__ int    hist[NUM_VOXELS];  // 2 KB (512 bins = 512 threads)
    __shared__ int    cur[NUM_VOXELS];   // 2 KB
    __shared__ int    wsum[8];

    const int t    = threadIdx.x;
    const int lane = t & 63;
    const int wid  = t >> 6;             // 8 waves
    const int i    = blockIdx.x * BLK + t;

    const int   v  = voxel_ids[i];
    const float x0 = X[3*i + 0];
    const float x1 = X[3*i + 1];
    const float x2 = X[3*i + 2];
    const int   r  = row_ids[i];         // stays in this thread's registers

    hist[t] = 0;
    __syncthreads();                                         // B1
    atomicAdd(&hist[v], 1);
    __syncthreads();                                         // B2

    // two-level exclusive scan over 512 bins (one bin per thread, 8 waves)
    const int c = hist[t];
    int incl = c;
    #pragma unroll
    for (int d = 1; d < 64; d <<= 1) {
        int n = __shfl_up(incl, d);
        if (lane >= d) incl += n;
    }
    if (lane == 63) wsum[wid] = incl;                        // wave totals
    __syncthreads();                                         // B3
    if (t < 64) {                                            // wave 0
        int s = (lane < 8) ? wsum[lane] : 0;
        #pragma unroll
        for (int d = 1; d < 8; d <<= 1) {
            int n = __shfl_up(s, d);
            if (lane >= d) s += n;
        }
        int excl = __shfl_up(s, 1);
        if (lane == 0) excl = 0;
        if (lane < 8) wsum[lane] = excl;                     // wave offsets
    }
    __syncthreads();                                         // B4
    cur[t] = wsum[wid] + incl - c;                           // exclusive prefix
    __syncthreads();                                         // B5

    const int mypos = atomicAdd(&cur[v], 1);     // own point's sorted slot
    pts[mypos] = make_float4(x0, x1, x2, __int_as_float(v));
    __syncthreads();                                         // B6

    // compute for the point sitting at slot t
    const float4 q  = pts[t];
    const int    sv = __float_as_int(q.w);
    float a0, a1, a2;
    posenc_pack_dot(q.x, q.y, q.z, Wp, sv, a0, a1, a2);

    pts[t] = make_float4(a0, a1, a2, 0.0f);      // same slot we read: no race
    __syncthreads();                                         // B7

    // unpermute: fetch own point's result, write in original (coalesced)
    // order; nontemporal (write-once, keep L2 for the Wp gather)
    const float4 res = pts[mypos];
    __builtin_nontemporal_store(res.x, &out[3*r + 0]);
    __builtin_nontemporal_store(res.y, &out[3*r + 1]);
    __builtin_nontemporal_store(res.z, &out[3*r + 2]);
}

// ---------------------------------------------------------------------------
// R1-style fallback if ws too small for the 192 KB packed table.
// ---------------------------------------------------------------------------
__global__ __launch_bounds__(256) void voxlin_fallback(
    const float* __restrict__ X, const float* __restrict__ W,
    const int* __restrict__ row_ids, const int* __restrict__ voxel_ids,
    float* __restrict__ out)
{
    const int i = blockIdx.x * 256 + threadIdx.x;
    if (i >= N_POINTS) return;
    const float x0 = X[3*i], x1 = X[3*i+1], x2 = X[3*i+2];
    const int v = voxel_ids[i];
    const float* __restrict__ w0 = W + v * 189;
    const float* __restrict__ w1 = w0 + 63;
    const float* __restrict__ w2 = w0 + 126;
    float a0 = x0*w0[0] + x1*w0[1] + x2*w0[2];
    float a1 = x0*w1[0] + x1*w1[1] + x2*w1[2];
    float a2 = x0*w2[0] + x1*w2[1] + x2*w2[2];
    float s0, c0, s1, c1, s2, c2;
    __sincosf(x0, &s0, &c0); __sincosf(x1, &s1, &c1); __sincosf(x2, &s2, &c2);
    #pragma unroll
    for (int f = 0; f < NUM_FREQS; ++f) {
        const int b = 3 + 6*f;
        a0 += s0*w0[b] + s1*w0[b+1] + s2*w0[b+2] + c0*w0[b+3] + c1*w0[b+4] + c2*w0[b+5];
        a1 += s0*w1[b] + s1*w1[b+1] + s2*w1[b+2] + c0*w1[b+3] + c1*w1[b+4] + c2*w1[b+5];
        a2 += s0*w2[b] + s1*w2[b+1] + s2*w2[b+2] + c0*w2[b+3] + c1*w2[b+4] + c2*w2[b+5];
        if (f < NUM_FREQS - 1) {
            const float ns0 = 2.0f*s0*c0, nc0 = c0*c0 - s0*s0;
            const float ns1 = 2.0f*s1*c1, nc1 = c1*c1 - s1*s1;
            const float ns2 = 2.0f*s2*c2, nc2 = c2*c2 - s2*s2;
            s0 = ns0; c0 = nc0; s1 = ns1; c1 = nc1; s2 = ns2; c2 = nc2;
        }
    }
    const int rr = row_ids[i];
    out[3*rr] = a0; out[3*rr+1] = a1; out[3*rr+2] = a2;
}

// ---------------------------------------------------------------------------
extern "C" void kernel_launch(void* const* d_in, const int* in_sizes, int n_in,
                              void* d_out, int out_size, void* d_ws, size_t ws_size,
                              hipStream_t stream) {
    const float* X         = (const float*)d_in[0];
    const float* W         = (const float*)d_in[1];
    const int*   row_ids   = (const int*)d_in[2];
    const int*   voxel_ids = (const int*)d_in[3];
    float*       out       = (float*)d_out;

    const size_t need = (size_t)NUM_VOXELS * 192 * sizeof(_Float16); // 192 KB

    if (ws_size >= need) {
        _Float16* Wp = (_Float16*)d_ws;
        pack_w<<<96, 1024, 0, stream>>>(W, Wp);
        voxlin_fused<<<NBLK, BLK, 0, stream>>>(X, Wp, row_ids, voxel_ids, out);
    } else {
        voxlin_fallback<<<(N_POINTS + 255) / 256, 256, 0, stream>>>(X, W, row_ids, voxel_ids, out);
    }
}

// Round 13
// 72.223 us; speedup vs baseline: 2.2479x; 1.0378x over previous
//
#include <hip/hip_runtime.h>
#include <math.h>

#define N_POINTS   262144
#define NUM_FREQS  10
#define NUM_VOXELS 512

// W is (1536,63) row-major fp32; voxel v uses rows 3v..3v+2 (189 floats).
// Packed into ws as fp16: Wp[v] = 3 rows x 64 halfs (col63 zero) = 384 B,
// 64B-aligned -> each point's gather is 24 uint4 loads over exactly 6 lines.
//
// R13 = exact revert to the R9 champion (71.03 us verified):
//   - block-local counting sort (1024-pt window) -> wave lanes share voxel
//     cache lines on the W gather
//   - LDS unpermute -> out-writes in original coalesced order
//   - fp16 weights + v_dot2_f32_f16 (fdot2 verified working on gfx950)
//   - enc packed as _Float16 (16 VGPRs) -> low register pressure
// R12's int8+sdot4 crashed: v_dot4_i32_i8 is not valid on gfx950 even though
// __has_builtin(__builtin_amdgcn_sdot4) is true. Do not use sdot4 here.

typedef _Float16 half2v __attribute__((ext_vector_type(2)));

__device__ __forceinline__ half2v u2h(unsigned int u) {
    union { unsigned int u; half2v h; } c; c.u = u; return c.h;
}

__device__ __forceinline__ float dot2acc(half2v a, half2v b, float acc) {
#if __has_builtin(__builtin_amdgcn_fdot2)
    return __builtin_amdgcn_fdot2(a, b, acc, false);
#else
    return acc + (float)a[0] * (float)b[0] + (float)a[1] * (float)b[1];
#endif
}

// ---------------------------------------------------------------------------
// Pass 1: pack W (fp32 1536x63) -> Wp (fp16 512 x 3 x 64). Runs every call
// (ws is re-poisoned before every timed launch).  96 blocks x 1024.
// ---------------------------------------------------------------------------
__global__ __launch_bounds__(1024) void pack_w(
    const float* __restrict__ W, _Float16* __restrict__ Wp)
{
    const int gid = blockIdx.x * 1024 + threadIdx.x;   // [0, 98304) = 512*192
    const int v = gid / 192, e = gid % 192;
    const int row = e >> 6, col = e & 63;
    Wp[v * 192 + e] = (col < 63) ? (_Float16)W[v * 189 + row * 63 + col]
                                 : (_Float16)0.0f;
}

// posenc (double-angle recurrence; 2^f*x exact in fp32, recurrence err ~1e-4)
// packed to half2, + dot against 3 fp16 rows of voxel v (24 uint4, 6 lines).
__device__ __forceinline__ void posenc_pack_dot(
    float x0, float x1, float x2, const _Float16* __restrict__ Wp, int v,
    float& a0, float& a1, float& a2)
{
    half2v eh[32];                       // 64 halfs = 16 VGPRs
#define SETE(p, val) eh[(p) >> 1][(p) & 1] = (_Float16)(val)
    SETE(0, x0); SETE(1, x1); SETE(2, x2);
    SETE(63, 0.0f);                      // pairs with zero pad col

    float s0, c0, s1, c1, s2, c2;
    __sincosf(x0, &s0, &c0);
    __sincosf(x1, &s1, &c1);
    __sincosf(x2, &s2, &c2);
    #pragma unroll
    for (int f = 0; f < NUM_FREQS; ++f) {
        const int b = 3 + 6*f;           // [s0 s1 s2 c0 c1 c2]
        SETE(b+0, s0); SETE(b+1, s1); SETE(b+2, s2);
        SETE(b+3, c0); SETE(b+4, c1); SETE(b+5, c2);
        if (f < NUM_FREQS - 1) {
            const float ns0 = 2.0f*s0*c0, nc0 = c0*c0 - s0*s0;
            const float ns1 = 2.0f*s1*c1, nc1 = c1*c1 - s1*s1;
            const float ns2 = 2.0f*s2*c2, nc2 = c2*c2 - s2*s2;
            s0 = ns0; c0 = nc0; s1 = ns1; c1 = nc1; s2 = ns2; c2 = nc2;
        }
    }
#undef SETE

    const uint4* __restrict__ wb = (const uint4*)(Wp + (size_t)v * 192);
    float acc[3];
    #pragma unroll
    for (int r = 0; r < 3; ++r) {
        float a = 0.0f;
        #pragma unroll
        for (int k = 0; k < 8; ++k) {
            const uint4 q = wb[r * 8 + k];
            a = dot2acc(u2h(q.x), eh[4*k + 0], a);
            a = dot2acc(u2h(q.y), eh[4*k + 1], a);
            a = dot2acc(u2h(q.z), eh[4*k + 2], a);
            a = dot2acc(u2h(q.w), eh[4*k + 3], a);
        }
        acc[r] = a;
    }
    a0 = acc[0]; a1 = acc[1]; a2 = acc[2];
}

// ---------------------------------------------------------------------------
// Pass 2: fused sort + compute + unpermute.  Grid = 256 x 1024 = N.
// ---------------------------------------------------------------------------
__global__ __launch_bounds__(1024) void voxlin_fused(
    const float* __restrict__ X,
    const _Float16* __restrict__ Wp,
    const int* __restrict__ row_ids,
    const int* __restrict__ voxel_ids,
    float* __restrict__ out)
{
    __shared__ float4 pts[1024];         // 16 KB: (x,y,z,v) then (a0,a1,a2,-)
    __shared__ int    hist[NUM_VOXELS];
    __shared__ int    cur[NUM_VOXELS];
    __shared__ int    wsum[8];

    const int t    = threadIdx.x;
    const int lane = t & 63;
    const int wid  = t >> 6;
    const int i    = blockIdx.x * 1024 + t;

    const int   v  = voxel_ids[i];
    const float x0 = X[3*i + 0];
    const float x1 = X[3*i + 1];
    const float x2 = X[3*i + 2];
    const int   r  = row_ids[i];         // stays in this thread's registers

    if (t < NUM_VOXELS) hist[t] = 0;
    __syncthreads();                                         // B1
    atomicAdd(&hist[v], 1);
    __syncthreads();                                         // B2

    // two-level exclusive scan over 512 bins (waves 0..7 active for level 1)
    int c = 0, incl = 0;
    if (t < NUM_VOXELS) {
        c = hist[t];
        incl = c;
        #pragma unroll
        for (int d = 1; d < 64; d <<= 1) {
            int n = __shfl_up(incl, d);
            if (lane >= d) incl += n;
        }
        if (lane == 63) wsum[wid] = incl;                    // wave totals
    }
    __syncthreads();                                         // B3
    if (t < 64) {                                            // wave 0
        int s = (lane < 8) ? wsum[lane] : 0;
        #pragma unroll
        for (int d = 1; d < 8; d <<= 1) {
            int n = __shfl_up(s, d);
            if (lane >= d) s += n;
        }
        int excl = __shfl_up(s, 1);
        if (lane == 0) excl = 0;
        if (lane < 8) wsum[lane] = excl;                     // chunk offsets
    }
    __syncthreads();                                         // B4
    if (t < NUM_VOXELS) cur[t] = wsum[wid] + incl - c;       // exclusive prefix
    __syncthreads();                                         // B5

    const int mypos = atomicAdd(&cur[v], 1);     // own point's sorted slot
    pts[mypos] = make_float4(x0, x1, x2, __int_as_float(v));
    __syncthreads();                                         // B6

    // compute for the point sitting at slot t
    const float4 q  = pts[t];
    const int    sv = __float_as_int(q.w);
    float a0, a1, a2;
    posenc_pack_dot(q.x, q.y, q.z, Wp, sv, a0, a1, a2);

    pts[t] = make_float4(a0, a1, a2, 0.0f);      // same slot we read: no race
    __syncthreads();                                         // B7

    // unpermute: fetch own point's result, write in original (coalesced) order
    const float4 res = pts[mypos];
    out[3*r + 0] = res.x;
    out[3*r + 1] = res.y;
    out[3*r + 2] = res.z;
}

// ---------------------------------------------------------------------------
// Fallback (R1 kernel) if ws too small for the 192 KB packed table.
// ---------------------------------------------------------------------------
__global__ __launch_bounds__(256) void voxlin_fallback(
    const float* __restrict__ X, const float* __restrict__ W,
    const int* __restrict__ row_ids, const int* __restrict__ voxel_ids,
    float* __restrict__ out)
{
    const int i = blockIdx.x * 256 + threadIdx.x;
    if (i >= N_POINTS) return;
    const float x0 = X[3*i], x1 = X[3*i+1], x2 = X[3*i+2];
    const int v = voxel_ids[i];
    const float* __restrict__ w0 = W + v * 189;
    const float* __restrict__ w1 = w0 + 63;
    const float* __restrict__ w2 = w0 + 126;
    float a0 = x0*w0[0] + x1*w0[1] + x2*w0[2];
    float a1 = x0*w1[0] + x1*w1[1] + x2*w1[2];
    float a2 = x0*w2[0] + x1*w2[1] + x2*w2[2];
    float s0, c0, s1, c1, s2, c2;
    __sincosf(x0, &s0, &c0); __sincosf(x1, &s1, &c1); __sincosf(x2, &s2, &c2);
    #pragma unroll
    for (int f = 0; f < NUM_FREQS; ++f) {
        const int b = 3 + 6*f;
        a0 += s0*w0[b] + s1*w0[b+1] + s2*w0[b+2] + c0*w0[b+3] + c1*w0[b+4] + c2*w0[b+5];
        a1 += s0*w1[b] + s1*w1[b+1] + s2*w1[b+2] + c0*w1[b+3] + c1*w1[b+4] + c2*w1[b+5];
        a2 += s0*w2[b] + s1*w2[b+1] + s2*w2[b+2] + c0*w2[b+3] + c1*w2[b+4] + c2*w2[b+5];
        if (f < NUM_FREQS - 1) {
            const float ns0 = 2.0f*s0*c0, nc0 = c0*c0 - s0*s0;
            const float ns1 = 2.0f*s1*c1, nc1 = c1*c1 - s1*s1;
            const float ns2 = 2.0f*s2*c2, nc2 = c2*c2 - s2*s2;
            s0 = ns0; c0 = nc0; s1 = ns1; c1 = nc1; s2 = ns2; c2 = nc2;
        }
    }
    const int rr = row_ids[i];
    out[3*rr] = a0; out[3*rr+1] = a1; out[3*rr+2] = a2;
}

// ---------------------------------------------------------------------------
extern "C" void kernel_launch(void* const* d_in, const int* in_sizes, int n_in,
                              void* d_out, int out_size, void* d_ws, size_t ws_size,
                              hipStream_t stream) {
    const float* X         = (const float*)d_in[0];
    const float* W         = (const float*)d_in[1];
    const int*   row_ids   = (const int*)d_in[2];
    const int*   voxel_ids = (const int*)d_in[3];
    float*       out       = (float*)d_out;

    const size_t need = (size_t)NUM_VOXELS * 192 * sizeof(_Float16); // 192 KB

    if (ws_size >= need) {
        _Float16* Wp = (_Float16*)d_ws;
        pack_w<<<96, 1024, 0, stream>>>(W, Wp);
        voxlin_fused<<<N_POINTS / 1024, 1024, 0, stream>>>(X, Wp, row_ids, voxel_ids, out);
    } else {
        voxlin_fallback<<<(N_POINTS + 255) / 256, 256, 0, stream>>>(X, W, row_ids, voxel_ids, out);
    }
}